// Round 1
// baseline (118.556 us; speedup 1.0000x reference)
//
#include <hip/hip_runtime.h>

// Problem shape (fixed by setup_inputs): n=32, m=16, p=1024, d=512.
// out[n,p,d] = feat[n,p,d] * mean_m(task[n,m,p])
//
// Memory-bound: 2MB task + 64MB feat read, 64MB write -> ~21us floor @6.3TB/s.
// One block per (n,p) row; 128 threads x float4 covers d=512 exactly.

#define N_DIM 32
#define M_DIM 16
#define P_DIM 1024
#define D_DIM 512

__global__ __launch_bounds__(128) void MAP_20023137534634_kernel(
    const float* __restrict__ task,   // [n, m, p]
    const float* __restrict__ feat,   // [n, p, d]
    float* __restrict__ out)          // [n, p, d]
{
    const int np = blockIdx.x;            // 0 .. N*P-1
    const int n  = np >> 10;              // / P_DIM (1024)
    const int p  = np & (P_DIM - 1);

    // mean over m of task[n, :, p] — stride-P scalar loads, wave-broadcast
    // (same address across lanes => 1 transaction/wave; task fits in L2).
    const float* tptr = task + ((size_t)n * M_DIM) * P_DIM + p;
    float s = 0.0f;
#pragma unroll
    for (int m = 0; m < M_DIM; ++m) {
        s += tptr[(size_t)m * P_DIM];
    }
    const float mean = s * (1.0f / (float)M_DIM);

    // elementwise scale of the 512-float row: 128 threads x float4
    const size_t base = (size_t)np * D_DIM;
    const float4* f4 = (const float4*)(feat + base);
    float4*       o4 = (float4*)(out + base);

    float4 v = f4[threadIdx.x];
    v.x *= mean; v.y *= mean; v.z *= mean; v.w *= mean;
    o4[threadIdx.x] = v;
}

extern "C" void kernel_launch(void* const* d_in, const int* in_sizes, int n_in,
                              void* d_out, int out_size, void* d_ws, size_t ws_size,
                              hipStream_t stream) {
    const float* task = (const float*)d_in[0];   // [32,16,1024] fp32
    const float* feat = (const float*)d_in[1];   // [32,1024,512] fp32
    float* out = (float*)d_out;                  // [32,1024,512] fp32

    dim3 grid(N_DIM * P_DIM);   // 32768 blocks
    dim3 block(128);            // 2 waves; 128*4 = 512 = D_DIM
    MAP_20023137534634_kernel<<<grid, block, 0, stream>>>(task, feat, out);
}

// Round 2
// 116.434 us; speedup vs baseline: 1.0182x; 1.0182x over previous
//
#include <hip/hip_runtime.h>

// Problem shape (fixed): n=32, m=16, p=1024, d=512.
// out[n,p,d] = feat[n,p,d] * mean_m(task[n,m,p])
//
// Two-kernel structure:
//   A) mean[n,p] = (1/16) * sum_m task[n,m,p]   (2MB read, 128KB write, ~2us)
//   B) out = feat * mean[row]                   (pure 128MB stream, ~21us @6.3TB/s)
// Kernel B reads mean via per-wave broadcast loads (same addr across lanes,
// 128KB table -> L1/L2 resident), so it is structurally a stream copy.

#define N_DIM 32
#define M_DIM 16
#define P_DIM 1024
#define D_DIM 512
#define NP    (N_DIM * P_DIM)            // 32768 rows
#define TOTAL4 (NP * (D_DIM / 4))        // 4,194,304 float4 elements

__global__ __launch_bounds__(256) void mean_kernel(
    const float* __restrict__ task,      // [n, m, p]
    float* __restrict__ mean)            // [n*p]
{
    const int i = blockIdx.x * 256 + threadIdx.x;   // 0..NP-1, consecutive p
    const int n = i >> 10;                          // / P_DIM
    const int p = i & (P_DIM - 1);
    const float* t = task + (size_t)n * M_DIM * P_DIM + p;
    float s = 0.0f;
#pragma unroll
    for (int m = 0; m < M_DIM; ++m) {
        s += t[(size_t)m * P_DIM];                  // coalesced across threads per m
    }
    mean[i] = s * (1.0f / (float)M_DIM);
}

__global__ __launch_bounds__(256) void scale_kernel(
    const float* __restrict__ feat,      // [n*p, d]
    const float* __restrict__ mean,      // [n*p]
    float* __restrict__ out)             // [n*p, d]
{
    const int idx4 = blockIdx.x * 256 + threadIdx.x;   // float4 index
    const float m = mean[idx4 >> 7];                   // d/4 = 128 float4s per row
    float4 v = ((const float4*)feat)[idx4];
    v.x *= m; v.y *= m; v.z *= m; v.w *= m;
    ((float4*)out)[idx4] = v;
}

extern "C" void kernel_launch(void* const* d_in, const int* in_sizes, int n_in,
                              void* d_out, int out_size, void* d_ws, size_t ws_size,
                              hipStream_t stream) {
    const float* task = (const float*)d_in[0];   // [32,16,1024] fp32
    const float* feat = (const float*)d_in[1];   // [32,1024,512] fp32
    float* out  = (float*)d_out;                 // [32,1024,512] fp32
    float* mean = (float*)d_ws;                  // 32768 floats = 128 KB scratch

    mean_kernel<<<dim3(NP / 256), dim3(256), 0, stream>>>(task, mean);
    scale_kernel<<<dim3(TOTAL4 / 256), dim3(256), 0, stream>>>(feat, mean, out);
}